// Round 1
// baseline (223.222 us; speedup 1.0000x reference)
//
#include <hip/hip_runtime.h>

// Shift2D: per-channel fractional 2D shift with bilinear interpolation.
// x: (N,C,H,W) fp32, weight: (C,2) fp32 -> out (N,C,H,W) fp32.
// Fixed problem size: N=16, C=256, H=128, W=128.

#define H_LOG2 7
#define W_LOG2 7
#define H_DIM 128
#define W_DIM 128

__global__ __launch_bounds__(256) void shift2d_kernel(
    const float* __restrict__ x,
    const float* __restrict__ w,
    float* __restrict__ out,
    long long total)
{
    long long idx = (long long)blockIdx.x * blockDim.x + threadIdx.x;
    if (idx >= total) return;

    const int j = (int)(idx & (W_DIM - 1));
    const int i = (int)((idx >> W_LOG2) & (H_DIM - 1));
    const long long p = idx >> (W_LOG2 + H_LOG2);   // n*C + c
    const int c = (int)(p & 255);                   // C = 256

    const float sy = w[2 * c + 0];
    const float sx = w[2 * c + 1];

    // vertical
    const float ysf = (float)i + sy;
    const float y0f = floorf(ysf);
    const float fy  = ysf - y0f;
    const int   y0  = (int)y0f;
    const int   y1  = y0 + 1;
    const float vy0 = (y0 >= 0 && y0 < H_DIM) ? 1.f : 0.f;
    const float vy1 = (y1 >= 0 && y1 < H_DIM) ? 1.f : 0.f;
    const int   y0c = min(max(y0, 0), H_DIM - 1);
    const int   y1c = min(max(y1, 0), H_DIM - 1);

    // horizontal
    const float xsf = (float)j + sx;
    const float x0f = floorf(xsf);
    const float fx  = xsf - x0f;
    const int   x0  = (int)x0f;
    const int   x1  = x0 + 1;
    const float vx0 = (x0 >= 0 && x0 < W_DIM) ? 1.f : 0.f;
    const float vx1 = (x1 >= 0 && x1 < W_DIM) ? 1.f : 0.f;
    const int   x0c = min(max(x0, 0), W_DIM - 1);
    const int   x1c = min(max(x1, 0), W_DIM - 1);

    const float wy0 = (1.f - fy) * vy0;
    const float wy1 = fy * vy1;
    const float wx0 = (1.f - fx) * vx0;
    const float wx1 = fx * vx1;

    const float* plane = x + (p << (W_LOG2 + H_LOG2));
    const float v00 = plane[(y0c << W_LOG2) + x0c];
    const float v01 = plane[(y0c << W_LOG2) + x1c];
    const float v10 = plane[(y1c << W_LOG2) + x0c];
    const float v11 = plane[(y1c << W_LOG2) + x1c];

    // match reference contraction order: rows along W first, then blend along H
    const float r0 = wx0 * v00 + wx1 * v01;
    const float r1 = wx0 * v10 + wx1 * v11;
    out[idx] = wy0 * r0 + wy1 * r1;
}

extern "C" void kernel_launch(void* const* d_in, const int* in_sizes, int n_in,
                              void* d_out, int out_size, void* d_ws, size_t ws_size,
                              hipStream_t stream) {
    const float* x = (const float*)d_in[0];
    const float* w = (const float*)d_in[1];
    float* out = (float*)d_out;

    const long long total = (long long)out_size;  // 16*256*128*128 = 67108864
    const int block = 256;
    const long long grid = (total + block - 1) / block;

    shift2d_kernel<<<(dim3)(unsigned)grid, block, 0, stream>>>(x, w, out, total);
}

// Round 2
// 120.926 us; speedup vs baseline: 1.8459x; 1.8459x over previous
//
#include <hip/hip_runtime.h>

// Shift2D: per-channel fractional 2D shift, bilinear, zero padding.
// x: (N,C,H,W)=(16,256,128,128) fp32, weight: (C,2) fp32.
// Key: floor(j+s) = j+floor(s); weight in [-1,1) => floor(s) in {-1,0}.
// Each thread produces 4 consecutive output pixels (one float4 store) and
// needs 5 consecutive input columns from 2 rows: aligned float4 + 1 scalar.

#define H_DIM 128
#define W_DIM 128

__global__ __launch_bounds__(256) void shift2d_kernel(
    const float* __restrict__ x,
    const float* __restrict__ w,
    float* __restrict__ out,
    int nQuads)
{
    const int q = blockIdx.x * blockDim.x + threadIdx.x;
    if (q >= nQuads) return;

    const int j0 = (q & 31) << 2;          // 32 quads per row
    const int i  = (q >> 5) & (H_DIM - 1);
    const int p  = q >> 12;                // plane index n*C + c
    const int c  = p & 255;                // C = 256

    const float sy = w[2 * c];
    const float sx = w[2 * c + 1];

    // vertical blend (uniform over the row)
    const float ysf = (float)i + sy;
    const float y0f = floorf(ysf);
    const float fy  = ysf - y0f;
    const int   y0  = (int)y0f;
    const int   y1  = y0 + 1;
    const float wy0 = (y0 >= 0 && y0 < H_DIM) ? (1.f - fy) : 0.f;
    const float wy1 = (y1 >= 0 && y1 < H_DIM) ? fy : 0.f;
    const int   y0c = min(max(y0, 0), H_DIM - 1);
    const int   y1c = min(max(y1, 0), H_DIM - 1);

    // horizontal: constant integer offset d + constant fraction fx
    const float x0f = floorf(sx);
    const float fx  = sx - x0f;
    const int   d   = (int)x0f;

    const float* plane = x + ((long long)p << 14);
    const float* r0 = plane + (y0c << 7);
    const float* r1 = plane + (y1c << 7);

    float4 o;

    if (d == 0) {
        // need cols j0..j0+4
        const float4 A0 = *(const float4*)(r0 + j0);
        const float4 A1 = *(const float4*)(r1 + j0);
        const int   ec = min(j0 + 4, W_DIM - 1);   // masked when j0==124
        const float s0 = wy0 * A0.x + wy1 * A1.x;
        const float s1 = wy0 * A0.y + wy1 * A1.y;
        const float s2 = wy0 * A0.z + wy1 * A1.z;
        const float s3 = wy0 * A0.w + wy1 * A1.w;
        const float s4 = wy0 * r0[ec] + wy1 * r1[ec];
        const float wx0 = 1.f - fx;
        const float wx1_last = (j0 < W_DIM - 4) ? fx : 0.f; // j=127: x1=128 invalid
        o.x = wx0 * s0 + fx * s1;
        o.y = wx0 * s1 + fx * s2;
        o.z = wx0 * s2 + fx * s3;
        o.w = wx0 * s3 + wx1_last * s4;
    } else if (d == -1) {
        // need cols j0-1..j0+3
        const float4 A0 = *(const float4*)(r0 + j0);
        const float4 A1 = *(const float4*)(r1 + j0);
        const int   ec = max(j0 - 1, 0);           // masked when j0==0
        const float sm = wy0 * r0[ec] + wy1 * r1[ec];
        const float s0 = wy0 * A0.x + wy1 * A1.x;
        const float s1 = wy0 * A0.y + wy1 * A1.y;
        const float s2 = wy0 * A0.z + wy1 * A1.z;
        const float s3 = wy0 * A0.w + wy1 * A1.w;
        const float wx0 = 1.f - fx;
        const float wx0_first = (j0 > 0) ? wx0 : 0.f; // j=0: x0=-1 invalid
        o.x = wx0_first * sm + fx * s0;
        o.y = wx0 * s0 + fx * s1;
        o.z = wx0 * s1 + fx * s2;
        o.w = wx0 * s2 + fx * s3;
    } else {
        // generic fallback for |shift| >= 1 (not hit for this input range)
        #pragma unroll
        for (int k = 0; k < 4; ++k) {
            const int j   = j0 + k;
            const int xx0 = j + d;
            const int xx1 = xx0 + 1;
            const float vx0 = (xx0 >= 0 && xx0 < W_DIM) ? 1.f : 0.f;
            const float vx1 = (xx1 >= 0 && xx1 < W_DIM) ? 1.f : 0.f;
            const int x0c = min(max(xx0, 0), W_DIM - 1);
            const int x1c = min(max(xx1, 0), W_DIM - 1);
            const float c0 = wy0 * r0[x0c] + wy1 * r1[x0c];
            const float c1 = wy0 * r0[x1c] + wy1 * r1[x1c];
            const float v = (1.f - fx) * vx0 * c0 + fx * vx1 * c1;
            if (k == 0) o.x = v; else if (k == 1) o.y = v;
            else if (k == 2) o.z = v; else o.w = v;
        }
    }

    *(float4*)(out + ((long long)q << 2)) = o;
}

extern "C" void kernel_launch(void* const* d_in, const int* in_sizes, int n_in,
                              void* d_out, int out_size, void* d_ws, size_t ws_size,
                              hipStream_t stream) {
    const float* x = (const float*)d_in[0];
    const float* w = (const float*)d_in[1];
    float* out = (float*)d_out;

    const int nQuads = out_size >> 2;   // 16777216
    const int block = 256;
    const int grid = (nQuads + block - 1) / block;

    shift2d_kernel<<<grid, block, 0, stream>>>(x, w, out, nQuads);
}

// Round 4
// 81.713 us; speedup vs baseline: 2.7318x; 1.4799x over previous
//
#include <hip/hip_runtime.h>

// Shift2D: per-channel fractional 2D shift, bilinear, zero padding.
// x: (N,C,H,W)=(16,256,128,128) fp32, weight: (C,2) fp32.
// floor(j+s) = j+floor(s); weight in [-1,1) => d = floor(s) in {-1,0}.
// Thread = 4 consecutive output pixels. Wave64 = 2 full rows of one plane,
// so d, fx, sy are wave-uniform and the 5th input column each quad needs is
// the neighbor lane's blended edge value -> one shuffle, zero scalar loads.
// Vmem per quad: 2x global_load_dwordx4 + 1x nontemporal store_dwordx4.

#define H_DIM 128
#define W_DIM 128

typedef float vfloat4 __attribute__((ext_vector_type(4)));  // clang-native for nontemporal builtin

__global__ __launch_bounds__(256) void shift2d_kernel(
    const float* __restrict__ x,
    const float* __restrict__ w,
    float* __restrict__ out,
    int nQuads)
{
    const int q = blockIdx.x * blockDim.x + threadIdx.x;
    if (q >= nQuads) return;

    const int j0 = (q & 31) << 2;          // 32 quads per row
    const int i  = (q >> 5) & (H_DIM - 1);
    const int p  = q >> 12;                // plane index n*C + c
    const int c  = p & 255;                // C = 256

    const float sy = w[2 * c];
    const float sx = w[2 * c + 1];

    // vertical blend (uniform over the row)
    const float ysf = (float)i + sy;
    const float y0f = floorf(ysf);
    const float fy  = ysf - y0f;
    const int   y0  = (int)y0f;
    const int   y1  = y0 + 1;
    const float wy0 = (y0 >= 0 && y0 < H_DIM) ? (1.f - fy) : 0.f;
    const float wy1 = (y1 >= 0 && y1 < H_DIM) ? fy : 0.f;
    const int   y0c = min(max(y0, 0), H_DIM - 1);
    const int   y1c = min(max(y1, 0), H_DIM - 1);

    // horizontal: wave-uniform integer offset d + fraction fx
    const float x0f = floorf(sx);
    const float fx  = sx - x0f;
    const int   d   = (int)x0f;

    const float* plane = x + ((long long)p << 14);
    const float* r0 = plane + (y0c << 7);
    const float* r1 = plane + (y1c << 7);

    const vfloat4 A0 = *(const vfloat4*)(r0 + j0);
    const vfloat4 A1 = *(const vfloat4*)(r1 + j0);

    // vertically blended row segment
    const float s0 = wy0 * A0.x + wy1 * A1.x;
    const float s1 = wy0 * A0.y + wy1 * A1.y;
    const float s2 = wy0 * A0.z + wy1 * A1.z;
    const float s3 = wy0 * A0.w + wy1 * A1.w;

    const float wx0 = 1.f - fx;
    vfloat4 o;

    if (d == 0) {
        // o[j] = wx0*s[j] + fx*s[j+1]; col j0+4 = next lane's s0.
        // Lanes where j0==124 have x1=128 out of range -> weight 0, so a
        // row-crossing shuffle value is harmless.
        const float s4 = __shfl_down(s0, 1);
        const float wx1_last = (j0 < W_DIM - 4) ? fx : 0.f;
        o.x = wx0 * s0 + fx * s1;
        o.y = wx0 * s1 + fx * s2;
        o.z = wx0 * s2 + fx * s3;
        o.w = wx0 * s3 + wx1_last * s4;
    } else if (d == -1) {
        // o[j] = wx0*s[j-1] + fx*s[j]; col j0-1 = prev lane's s3.
        // Lanes where j0==0 have x0=-1 -> weight 0.
        const float sm = __shfl_up(s3, 1);
        const float wx0_first = (j0 > 0) ? wx0 : 0.f;
        o.x = wx0_first * sm + fx * s0;
        o.y = wx0 * s0 + fx * s1;
        o.z = wx0 * s1 + fx * s2;
        o.w = wx0 * s2 + fx * s3;
    } else {
        // generic fallback for |shift| >= 1 (not hit for weight in [-1,1))
        #pragma unroll
        for (int k = 0; k < 4; ++k) {
            const int j   = j0 + k;
            const int xx0 = j + d;
            const int xx1 = xx0 + 1;
            const float vx0 = (xx0 >= 0 && xx0 < W_DIM) ? 1.f : 0.f;
            const float vx1 = (xx1 >= 0 && xx1 < W_DIM) ? 1.f : 0.f;
            const int x0c = min(max(xx0, 0), W_DIM - 1);
            const int x1c = min(max(xx1, 0), W_DIM - 1);
            const float c0 = wy0 * r0[x0c] + wy1 * r1[x0c];
            const float c1 = wy0 * r0[x1c] + wy1 * r1[x1c];
            const float v = (1.f - fx) * vx0 * c0 + fx * vx1 * c1;
            if (k == 0) o.x = v; else if (k == 1) o.y = v;
            else if (k == 2) o.z = v; else o.w = v;
        }
    }

    __builtin_nontemporal_store(o, (vfloat4*)(out + ((long long)q << 2)));
}

extern "C" void kernel_launch(void* const* d_in, const int* in_sizes, int n_in,
                              void* d_out, int out_size, void* d_ws, size_t ws_size,
                              hipStream_t stream) {
    const float* x = (const float*)d_in[0];
    const float* w = (const float*)d_in[1];
    float* out = (float*)d_out;

    const int nQuads = out_size >> 2;   // 16777216
    const int block = 256;
    const int grid = (nQuads + block - 1) / block;

    shift2d_kernel<<<grid, block, 0, stream>>>(x, w, out, nQuads);
}

// Round 5
// 81.030 us; speedup vs baseline: 2.7548x; 1.0084x over previous
//
#include <hip/hip_runtime.h>

// Shift2D: per-channel fractional 2D shift, bilinear, zero padding.
// x: (N,C,H,W)=(16,256,128,128) fp32, weight: (C,2) fp32.
// floor(j+s)=j+floor(s); weight in [-1,1) => d=floor(s) in {-1,0}.
// Thread = 2 adjacent output rows x 4 cols (8 px). Vertically adjacent
// output rows share the middle input row: 3 row loads (dwordx4) + 2 NT
// stores per 8 px (vs 4+2 naive). The 5th input column per row comes from
// the neighbor lane's blended edge value via shuffle (d is wave-uniform).

#define H_DIM 128
#define W_DIM 128

typedef float vfloat4 __attribute__((ext_vector_type(4)));

__device__ __forceinline__ vfloat4 hblend0(vfloat4 s, float edge, float wx0, float fx, float wlast) {
    // d==0: o[k] = wx0*s[k] + fx*s[k+1], edge = next lane's s0
    vfloat4 o;
    o.x = wx0 * s.x + fx * s.y;
    o.y = wx0 * s.y + fx * s.z;
    o.z = wx0 * s.z + fx * s.w;
    o.w = wx0 * s.w + wlast * edge;
    return o;
}

__device__ __forceinline__ vfloat4 hblendm1(vfloat4 s, float edge, float wx0, float fx, float wfirst) {
    // d==-1: o[k] = wx0*s[k-1] + fx*s[k], edge = prev lane's s3
    vfloat4 o;
    o.x = wfirst * edge + fx * s.x;
    o.y = wx0 * s.x + fx * s.y;
    o.z = wx0 * s.y + fx * s.z;
    o.w = wx0 * s.z + fx * s.w;
    return o;
}

__global__ __launch_bounds__(256) void shift2d_kernel(
    const float* __restrict__ x,
    const float* __restrict__ w,
    float* __restrict__ out,
    int nThreads)
{
    const int t = blockIdx.x * blockDim.x + threadIdx.x;
    if (t >= nThreads) return;

    const int jb = t & 31;            // col quad index
    const int j0 = jb << 2;
    const int ib = (t >> 5) & 63;     // row-pair index
    const int i0 = ib << 1;
    const int p  = t >> 11;           // plane index n*C + c
    const int c  = p & 255;           // C = 256

    const float sy = w[2 * c];
    const float sx = w[2 * c + 1];

    // vertical: rows Y, Y+1, Y+2 cover output rows i0, i0+1
    const float dyf = floorf(sy);
    const float fy  = sy - dyf;            // frac(i+sy) is i-independent
    const int   Y   = i0 + (int)dyf;
    const int   R0 = Y, R1 = Y + 1, R2 = Y + 2;
    const bool  vA = (R0 >= 0) & (R0 < H_DIM);
    const bool  vB = (R1 >= 0) & (R1 < H_DIM);
    const bool  vC = (R2 >= 0) & (R2 < H_DIM);
    const int   R0c = min(max(R0, 0), H_DIM - 1);
    const int   R1c = min(max(R1, 0), H_DIM - 1);
    const int   R2c = min(max(R2, 0), H_DIM - 1);

    // horizontal: wave-uniform integer offset d + fraction fx
    const float dxf = floorf(sx);
    const float fx  = sx - dxf;
    const int   d   = (int)dxf;

    const float* plane = x + ((long long)p << 14);
    float* ob = out + (((long long)p << 14) + (i0 << 7) + j0);

    if (d == 0 || d == -1) {
        const vfloat4 A = *(const vfloat4*)(plane + (R0c << 7) + j0);
        const vfloat4 B = *(const vfloat4*)(plane + (R1c << 7) + j0);
        const vfloat4 C = *(const vfloat4*)(plane + (R2c << 7) + j0);

        const float w1  = fy;
        const float w0  = 1.f - fy;
        const float w0a = vA ? w0 : 0.f;
        const float w1b = vB ? w1 : 0.f;
        const float w0b = vB ? w0 : 0.f;
        const float w1c = vC ? w1 : 0.f;

        const vfloat4 sR0 = w0a * A + w1b * B;   // blended segment, output row i0
        const vfloat4 sR1 = w0b * B + w1c * C;   // blended segment, output row i0+1

        const float wx0 = 1.f - fx;
        vfloat4 o0, o1;
        if (d == 0) {
            // edge col j0+4 = next lane's s0; lanes with j0==124 masked (x1=128)
            const float e0 = __shfl_down(sR0.x, 1);
            const float e1 = __shfl_down(sR1.x, 1);
            const float wlast = (j0 < W_DIM - 4) ? fx : 0.f;
            o0 = hblend0(sR0, e0, wx0, fx, wlast);
            o1 = hblend0(sR1, e1, wx0, fx, wlast);
        } else {
            // edge col j0-1 = prev lane's s3; lanes with j0==0 masked (x0=-1)
            const float e0 = __shfl_up(sR0.w, 1);
            const float e1 = __shfl_up(sR1.w, 1);
            const float wfirst = (j0 > 0) ? wx0 : 0.f;
            o0 = hblendm1(sR0, e0, wx0, fx, wfirst);
            o1 = hblendm1(sR1, e1, wx0, fx, wfirst);
        }
        __builtin_nontemporal_store(o0, (vfloat4*)ob);
        __builtin_nontemporal_store(o1, (vfloat4*)(ob + W_DIM));
    } else {
        // generic fallback for |shift| >= 1 (never taken for weight in [-1,1))
        const float w0 = 1.f - fy, w1 = fy;
        const float w0a = vA ? w0 : 0.f;
        const float w1b = vB ? w1 : 0.f;
        const float w0b = vB ? w0 : 0.f;
        const float w1c = vC ? w1 : 0.f;
        const float* rA = plane + (R0c << 7);
        const float* rB = plane + (R1c << 7);
        const float* rC = plane + (R2c << 7);
        #pragma unroll
        for (int k = 0; k < 4; ++k) {
            const int j   = j0 + k;
            const int xx0 = j + d;
            const int xx1 = xx0 + 1;
            const float vx0 = (xx0 >= 0 && xx0 < W_DIM) ? 1.f : 0.f;
            const float vx1 = (xx1 >= 0 && xx1 < W_DIM) ? 1.f : 0.f;
            const int x0c = min(max(xx0, 0), W_DIM - 1);
            const int x1c = min(max(xx1, 0), W_DIM - 1);
            const float c00 = w0a * rA[x0c] + w1b * rB[x0c];
            const float c01 = w0a * rA[x1c] + w1b * rB[x1c];
            const float c10 = w0b * rB[x0c] + w1c * rC[x0c];
            const float c11 = w0b * rB[x1c] + w1c * rC[x1c];
            ob[k]         = (1.f - fx) * vx0 * c00 + fx * vx1 * c01;
            ob[W_DIM + k] = (1.f - fx) * vx0 * c10 + fx * vx1 * c11;
        }
    }
}

extern "C" void kernel_launch(void* const* d_in, const int* in_sizes, int n_in,
                              void* d_out, int out_size, void* d_ws, size_t ws_size,
                              hipStream_t stream) {
    const float* x = (const float*)d_in[0];
    const float* w = (const float*)d_in[1];
    float* out = (float*)d_out;

    const int nThreads = out_size >> 3;   // 8 px per thread = 8388608
    const int block = 256;
    const int grid = (nThreads + block - 1) / block;

    shift2d_kernel<<<grid, block, 0, stream>>>(x, w, out, nThreads);
}